// Round 3
// baseline (162.743 us; speedup 1.0000x reference)
//
#include <hip/hip_runtime.h>
#include <float.h>
#include <math.h>

#define NREF 100
#define NREF_PAD 128
#define DIM 256
#define K 5
#define ROWS 16         // x rows per block
#define BLOCK 256
#define DCHUNK 64       // d staged per iteration; numpy block = 128 = 2 chunks
#define SW 66           // staging inner width (dwords): 2-way conflicts only

// LDS: staging (x rows + ref rows) reused as the per-row key matrix afterwards.
union SM {
  struct {
    float x_s[ROWS * SW];        // [row][d]  4224 B
    float r_s[NREF_PAD * SW];    // [ref][d] 33792 B
  } s;
  float keys[ROWS * 132];        // [row][ref] 8448 B
};

__global__ __launch_bounds__(BLOCK, 4) void knn_kernel(
    const float* __restrict__ x, const float* __restrict__ ref,
    int* __restrict__ out, int nrows) {
#pragma clang fp contract(off)
  __shared__ SM sm;
  const int tid = threadIdx.x;
  const int tx = tid & 31;   // refs: tx, tx+32, tx+64, tx+96
  const int ty = tid >> 5;   // rows: 2*ty, 2*ty+1
  const int RB = blockIdx.x * ROWS;

  // numpy pairwise state: 8 accumulators per (row, ref) pair, per 128-block
  float acc[2][4][8];
  float part[2][4];   // sum of d-block 0..127
#pragma unroll
  for (int i = 0; i < 2; i++)
#pragma unroll
    for (int r = 0; r < 4; r++) {
      part[i][r] = 0.f;
#pragma unroll
      for (int j = 0; j < 8; j++) acc[i][r][j] = 0.f;
    }

  for (int c = 0; c < DIM / DCHUNK; c++) {
    const int DB = c * DCHUNK;
    if (c) __syncthreads();  // previous chunk fully consumed
    // ---- stage refs: 128 rows x 64 d (pad rows zero; never selected)
#pragma unroll
    for (int k = 0; k < 8; k++) {
      const int ii = tid + k * BLOCK;   // 2048 float4 slots
      const int r = ii >> 4;
      const int dp = (ii & 15) << 2;
      float4 v = make_float4(0.f, 0.f, 0.f, 0.f);
      if (r < NREF)
        v = *reinterpret_cast<const float4*>(ref + (size_t)r * DIM + DB + dp);
      float* dst = &sm.s.r_s[r * SW + dp];
      dst[0] = v.x; dst[1] = v.y; dst[2] = v.z; dst[3] = v.w;
    }
    // ---- stage x: 16 rows x 64 d
    {
      const int row = tid >> 4;
      const int dp = (tid & 15) << 2;
      float4 v = make_float4(0.f, 0.f, 0.f, 0.f);
      if (RB + row < nrows)
        v = *reinterpret_cast<const float4*>(x + (size_t)(RB + row) * DIM + DB + dp);
      float* dst = &sm.s.x_s[row * SW + dp];
      dst[0] = v.x; dst[1] = v.y; dst[2] = v.z; dst[3] = v.w;
    }
    __syncthreads();
    // ---- numpy 8-accumulator inner loop (fp contract OFF: no fma)
    for (int ib = 0; ib < DCHUNK; ib += 8) {
      float xv[2][8];
#pragma unroll
      for (int i = 0; i < 2; i++) {
        const float* xp = &sm.s.x_s[(2 * ty + i) * SW + ib];
#pragma unroll
        for (int jp = 0; jp < 4; jp++)
          *reinterpret_cast<float2*>(&xv[i][2 * jp]) =
              *reinterpret_cast<const float2*>(xp + 2 * jp);
      }
#pragma unroll
      for (int rr = 0; rr < 4; rr++) {
        float rv[8];
        const float* rp = &sm.s.r_s[(tx + 32 * rr) * SW + ib];
#pragma unroll
        for (int jp = 0; jp < 4; jp++)
          *reinterpret_cast<float2*>(&rv[2 * jp]) =
              *reinterpret_cast<const float2*>(rp + 2 * jp);
#pragma unroll
        for (int j = 0; j < 8; j++) {
          float d0 = xv[0][j] - rv[j];
          float s0 = d0 * d0;
          acc[0][rr][j] = acc[0][rr][j] + s0;
          float d1 = xv[1][j] - rv[j];
          float s1 = d1 * d1;
          acc[1][rr][j] = acc[1][rr][j] + s1;
        }
      }
    }
    // ---- end of a 128-d numpy block: collapse accumulators
    if (c & 1) {
#pragma unroll
      for (int i = 0; i < 2; i++)
#pragma unroll
        for (int r = 0; r < 4; r++) {
          float* a = acc[i][r];
          float res = ((a[0] + a[1]) + (a[2] + a[3])) +
                      ((a[4] + a[5]) + (a[6] + a[7]));
          if (c == 1) part[i][r] = res;
          else part[i][r] = part[i][r] + res;  // total = left + right
#pragma unroll
          for (int j = 0; j < 8; j++) a[j] = 0.f;
        }
    }
  }
  __syncthreads();  // staging LDS dead; reuse as keys
#pragma unroll
  for (int i = 0; i < 2; i++)
#pragma unroll
    for (int rr = 0; rr < 4; rr++)
      sm.keys[(2 * ty + i) * 132 + tx + 32 * rr] = sqrtf(part[i][rr]);
  __syncthreads();
  // ---- top-5 per row: strict < insertion => lowest index wins ties
  if (tid < ROWS && RB + tid < nrows) {
    float best[K];
    int bidx[K];
#pragma unroll
    for (int k = 0; k < K; k++) { best[k] = FLT_MAX; bidx[k] = 0; }
    for (int r = 0; r < NREF; r++) {
      const float kv = sm.keys[tid * 132 + r];
      if (kv < best[K - 1]) {
        int pos = K - 1;
        while (pos > 0 && kv < best[pos - 1]) {
          best[pos] = best[pos - 1];
          bidx[pos] = bidx[pos - 1];
          pos--;
        }
        best[pos] = kv;
        bidx[pos] = r;
      }
    }
    int* o = out + (size_t)(RB + tid) * K;
#pragma unroll
    for (int k = 0; k < K; k++) o[k] = bidx[k];
  }
}

extern "C" void kernel_launch(void* const* d_in, const int* in_sizes, int n_in,
                              void* d_out, int out_size, void* d_ws, size_t ws_size,
                              hipStream_t stream) {
  const float* x = (const float*)d_in[0];
  const float* ref = (const float*)d_in[1];
  int* out = (int*)d_out;
  const int nrows = in_sizes[0] / DIM;  // 16384
  const int grid = (nrows + ROWS - 1) / ROWS;  // 1024
  knn_kernel<<<grid, BLOCK, 0, stream>>>(x, ref, out, nrows);
}

// Round 4
// 128.138 us; speedup vs baseline: 1.2701x; 1.2701x over previous
//
#include <hip/hip_runtime.h>
#include <float.h>
#include <math.h>

#define NREF 100
#define NREF_PAD 128
#define DIM 256
#define K 5
#define ROWS 32
#define BLOCK 128
#define LDS_DW_REF 4096   // ref region base (dwords): x tile is 32*128 = 4096 dw

// LDS layout per 128-d chunk, per row: slot (jp,t) at dwords jp*32+2t holds
// d = {8t+2jp, 8t+2jp+1}. Swizzle dw ^= (dw>>8)&0x1C (row-octet keyed) makes
// all compute ds_read_b128 <=2-way. Total 80 KB static (gfx950 has 160 KB/CU).
__shared__ float lds_buf[20480];

__device__ __forceinline__ int swz(int dw) { return dw ^ ((dw >> 8) & 0x1C); }

__global__ __launch_bounds__(BLOCK, 1) void knn_kernel(
    const float* __restrict__ x, const float* __restrict__ ref,
    int* __restrict__ out, int nrows) {
#pragma clang fp contract(off)
  float* lds = lds_buf;
  const int tid = threadIdx.x;
  const int tx = tid & 15;   // ref block: refs 8*tx .. 8*tx+7
  const int ty = tid >> 4;   // row block: rows 4*ty .. 4*ty+3
  const int RB = blockIdx.x * ROWS;

  float part[4][8], t01[4][8], t45[4][8], ae[4][8], ao[4][8];

  const int xlin0 = (4 * ty) * 128;               // dw base of row block
  const int rlin0 = LDS_DW_REF + (tx * 8) * 128;  // dw base of ref block
  const int xkey = (xlin0 >> 8) & 0x1C;           // per-thread constant XOR
  const int rkey = (rlin0 >> 8) & 0x1C;

#pragma unroll 1
  for (int c = 0; c < 2; c++) {
    const int DB = c * 128;
    if (c) __syncthreads();  // chunk-0 reads done before restaging
    // ---- stage x: 32 rows x 128 d (1024 float4), scatter to (jp,t) slots
#pragma unroll
    for (int k = 0; k < 8; k++) {
      const int idx = tid + k * BLOCK;
      const int row = idx >> 5, dp4 = idx & 31;
      float4 v = make_float4(0.f, 0.f, 0.f, 0.f);
      if (RB + row < nrows)
        v = *reinterpret_cast<const float4*>(x + (size_t)(RB + row) * DIM + DB + dp4 * 4);
      const int t = dp4 >> 1;
      const int jp0 = (dp4 & 1) << 1;              // d%8<4 -> jp 0,1 ; else 2,3
      const int dwA = row * 128 + jp0 * 32 + 2 * t;
      *reinterpret_cast<float2*>(&lds[swz(dwA)]) = make_float2(v.x, v.y);
      *reinterpret_cast<float2*>(&lds[swz(dwA + 32)]) = make_float2(v.z, v.w);
    }
    // ---- stage refs: 100 real rows (pad rows left uninit; never consumed)
#pragma unroll
    for (int k = 0; k < 32; k++) {
      const int idx = tid + k * BLOCK;
      const int r = idx >> 5, dp4 = idx & 31;
      if (r < NREF) {
        const float4 v = *reinterpret_cast<const float4*>(ref + (size_t)r * DIM + DB + dp4 * 4);
        const int t = dp4 >> 1;
        const int jp0 = (dp4 & 1) << 1;
        const int dwA = LDS_DW_REF + r * 128 + jp0 * 32 + 2 * t;
        *reinterpret_cast<float2*>(&lds[swz(dwA)]) = make_float2(v.x, v.y);
        *reinterpret_cast<float2*>(&lds[swz(dwA + 32)]) = make_float2(v.z, v.w);
      }
    }
    __syncthreads();

    // ---- 4 jp phases; numpy accumulator j=2jp (ae), j=2jp+1 (ao)
#pragma unroll
    for (int jp = 0; jp < 4; jp++) {
#pragma unroll
      for (int i = 0; i < 4; i++)
#pragma unroll
        for (int rr = 0; rr < 8; rr++) { ae[i][rr] = 0.f; ao[i][rr] = 0.f; }
#pragma unroll 1
      for (int tt = 0; tt < 8; tt++) {  // t = 2*tt, 2*tt+1 per read
        const int xa = (xlin0 + jp * 32) + ((4 * tt) ^ xkey);
        const int ra = (rlin0 + jp * 32) + ((4 * tt) ^ rkey);
        float4 xv[4], rv[8];
#pragma unroll
        for (int i = 0; i < 4; i++)
          xv[i] = *reinterpret_cast<const float4*>(&lds[xa + i * 128]);
#pragma unroll
        for (int rr = 0; rr < 8; rr++)
          rv[rr] = *reinterpret_cast<const float4*>(&lds[ra + rr * 128]);
        // float4 = [e(t), o(t), e(t+1), o(t+1)]; adds kept t-ascending
#pragma unroll
        for (int i = 0; i < 4; i++)
#pragma unroll
          for (int rr = 0; rr < 8; rr++) {
            float d0 = xv[i].x - rv[rr].x; float s0 = d0 * d0; ae[i][rr] = ae[i][rr] + s0;
            float d1 = xv[i].z - rv[rr].z; float s1 = d1 * d1; ae[i][rr] = ae[i][rr] + s1;
            float d2 = xv[i].y - rv[rr].y; float s2 = d2 * d2; ao[i][rr] = ao[i][rr] + s2;
            float d3 = xv[i].w - rv[rr].w; float s3 = d3 * d3; ao[i][rr] = ao[i][rr] + s3;
          }
      }
      // ---- numpy tree fold: ((r0+r1)+(r2+r3)) + ((r4+r5)+(r6+r7))
#pragma unroll
      for (int i = 0; i < 4; i++)
#pragma unroll
        for (int rr = 0; rr < 8; rr++) {
          const float s = ae[i][rr] + ao[i][rr];
          if (jp == 0) t01[i][rr] = s;
          else if (jp == 1) t01[i][rr] = t01[i][rr] + s;      // s0123
          else if (jp == 2) t45[i][rr] = s;
          else {
            t45[i][rr] = t45[i][rr] + s;                      // s4567
            const float blk = t01[i][rr] + t45[i][rr];
            part[i][rr] = c ? (part[i][rr] + blk) : blk;      // total = L + R
          }
        }
    }
  }
  __syncthreads();  // staging dead; reuse LDS for keys, stride 129
#pragma unroll
  for (int i = 0; i < 4; i++)
#pragma unroll
    for (int rr = 0; rr < 8; rr++)
      lds[(4 * ty + i) * 129 + tx * 8 + rr] = sqrtf(part[i][rr]);
  __syncthreads();
  // ---- top-5: strict < insertion => lowest index wins ties (lax.top_k)
  if (tid < ROWS && RB + tid < nrows) {
    float best[K]; int bidx[K];
#pragma unroll
    for (int k = 0; k < K; k++) { best[k] = FLT_MAX; bidx[k] = 0; }
    for (int r = 0; r < NREF; r++) {
      const float kv = lds[tid * 129 + r];
      if (kv < best[K - 1]) {
        int pos = K - 1;
        while (pos > 0 && kv < best[pos - 1]) {
          best[pos] = best[pos - 1]; bidx[pos] = bidx[pos - 1]; pos--;
        }
        best[pos] = kv; bidx[pos] = r;
      }
    }
    int* o = out + (size_t)(RB + tid) * K;
#pragma unroll
    for (int k = 0; k < K; k++) o[k] = bidx[k];
  }
}

extern "C" void kernel_launch(void* const* d_in, const int* in_sizes, int n_in,
                              void* d_out, int out_size, void* d_ws, size_t ws_size,
                              hipStream_t stream) {
  const float* x = (const float*)d_in[0];
  const float* ref = (const float*)d_in[1];
  int* out = (int*)d_out;
  const int nrows = in_sizes[0] / DIM;  // 16384
  const int grid = (nrows + ROWS - 1) / ROWS;  // 512
  knn_kernel<<<grid, BLOCK, 0, stream>>>(x, ref, out, nrows);
}